// Round 13
// baseline (117.028 us; speedup 1.0000x reference)
//
#include <hip/hip_runtime.h>
#include <hip/hip_bf16.h>
#include <math.h>

// Modulated SIREN over 2-bit coordinate fields. Reference is a float32
// re-execution; network is chaotic (layer-1 sin errors amplify ~3e5 to the
// output, layer-2 ~1.5e4) so layer 1 keeps libm sinf + exact f32 chain;
// layer 2 uses sin30 (~3e-7 abs, injects <=5e-3); layers 3-4 use
// sincos30 + angle-addition tables.
// Layer-4 GEMM on MFMA via exact bf16 2-term split (K=768), 64x256 tiles,
// grid 1024 (4 blocks/CU -> 4 independent barrier groups hide the
// vmcnt(0)-at-barrier DMA drain), global_load_lds(16B) double-buffered LDS
// with 2-way granule swizzle (conflict-free, verified round 12).
// SC stored with permuted columns (p = wn|l15<<2|cf) so the epilogue writes
// dwordx4; B2u uses the same K-permutation (k_ugemm is permutation-invariant).
// Final layer: U = SCbf @ B2^T -> every (c3,i3) answer; point = 12B lookup.

typedef float  f32x4  __attribute__((ext_vector_type(4)));
typedef int    i32x4  __attribute__((ext_vector_type(4)));
typedef __bf16 bf16x8 __attribute__((ext_vector_type(8)));

__device__ __forceinline__ float fbar(float v) {
  asm volatile("" : "+v"(v));
  return v;
}

__device__ __forceinline__ unsigned short f2bf_rne(float x) {
  unsigned u = __float_as_uint(x);
  unsigned r = (u + 0x7fffu + ((u >> 16) & 1u)) >> 16;
  return (unsigned short)r;
}

// async global->LDS, 16B per lane; LDS dest = wave-uniform base + lane*16
__device__ __forceinline__ void gload16(const void* g, void* l) {
  __builtin_amdgcn_global_load_lds(
      (const __attribute__((address_space(1))) unsigned*)g,
      (__attribute__((address_space(3))) unsigned*)l, 16, 0, 0);
}

// sin(30*x): double-single range reduction by 30/2pi, rint half-period fold,
// deg-11 odd Taylor, parity sign. ~3e-7 abs.
__device__ __forceinline__ float sin30(float x) {
  const float Ch = 4.774648189544678f;
  const float Cl = 1.0321218e-07f;
  float revh = x * Ch;
  fbar(revh);
  float e    = __builtin_fmaf(x, Ch, -revh);
  float revl = __builtin_fmaf(x, Cl, e);
  float k2   = __builtin_rintf(revh + revh);
  float g    = __builtin_fmaf(k2, -0.5f, revh) + revl;
  float g2 = g * g;
  float r = -15.0946f;
  r = __builtin_fmaf(r, g2, 42.0601f);
  r = __builtin_fmaf(r, g2, -76.70585f);
  r = __builtin_fmaf(r, g2, 81.6052492f);
  r = __builtin_fmaf(r, g2, -41.341702f);
  r = __builtin_fmaf(r, g2, 6.2831853f);
  float s = g * r;
  int ki = (int)k2;
  return __uint_as_float(__float_as_uint(s) ^ ((unsigned)(ki & 1) << 31));
}

// sin(30*x) AND cos(30*x): shared range reduction, odd+even Taylor polys.
__device__ __forceinline__ void sincos30(float x, float* so, float* co) {
  const float Ch = 4.774648189544678f;
  const float Cl = 1.0321218e-07f;
  float revh = x * Ch;
  fbar(revh);
  float e    = __builtin_fmaf(x, Ch, -revh);
  float revl = __builtin_fmaf(x, Cl, e);
  float k2   = __builtin_rintf(revh + revh);
  float g    = __builtin_fmaf(k2, -0.5f, revh) + revl;
  float u = g * g;
  float sr = -15.0946f;
  sr = __builtin_fmaf(sr, u, 42.0601f);
  sr = __builtin_fmaf(sr, u, -76.70585f);
  sr = __builtin_fmaf(sr, u, 81.6052492f);
  sr = __builtin_fmaf(sr, u, -41.341702f);
  sr = __builtin_fmaf(sr, u, 6.2831853f);
  float s = g * sr;
  float cr = -26.4259f;
  cr = __builtin_fmaf(cr, u, 60.2446f);
  cr = __builtin_fmaf(cr, u, -85.4568f);
  cr = __builtin_fmaf(cr, u, 64.9393940f);
  cr = __builtin_fmaf(cr, u, -19.7392088f);
  float c = __builtin_fmaf(cr, u, 1.0f);
  int ki = (int)k2;
  unsigned sgn = ((unsigned)(ki & 1)) << 31;
  *so = __uint_as_float(__float_as_uint(s) ^ sgn);
  *co = __uint_as_float(__float_as_uint(c) ^ sgn);
}

// Fused prep:
//  blocks 0-63   : Mf[j][i] = emb[j][i]@modW[j] (exact seq fma).
//                  j==2 -> also T2C/T2S (layer-3 angle tables)
//                  j==3 -> also B2u (final-layer B, K-permuted like SC)
//  blocks 64-319 : B2T split [Bh;Bl;Bh] for the layer-4 GEMM.
__global__ void k_prep(const float* __restrict__ emb, const float* __restrict__ modW,
                       float* __restrict__ Mf, float* __restrict__ T2C,
                       float* __restrict__ T2S, const float* __restrict__ Wl,
                       unsigned* __restrict__ B2u, const float* __restrict__ W2,
                       unsigned short* __restrict__ B2T) {
  int b = blockIdx.x, d = threadIdx.x;
  if (b < 64) {
    int j = b >> 4, i = b & 15;
    float acc = 0.0f;
#pragma unroll
    for (int e = 0; e < 16; ++e)
      acc = __builtin_fmaf(emb[j * 256 + i * 16 + e], modW[(j * 16 + e) * 256 + d], acc);
    Mf[b * 256 + d] = acc;
    if (j == 2) {
      float pm = fbar(30.0f * acc);
      float s, c;
      sincos30(pm, &s, &c);
      T2C[i * 256 + d] = c;
      T2S[i * 256 + d] = s;
    } else if (j == 3) {
      float pm = fbar(30.0f * acc);
      float s, c;
      sincos30(pm, &s, &c);
      // same column permutation as k_gemm's SC store
      int p = (d & 0xC0) | ((d & 15) << 2) | ((d >> 4) & 3);
#pragma unroll
      for (int q = 0; q < 3; ++q) {
        float w = Wl[d * 3 + q];
        unsigned ts = (unsigned)f2bf_rne(s * w);
        unsigned tc = (unsigned)f2bf_rne(c * w);
        B2u[(i * 3 + q) * 256 + p] = (tc << 16) | ts;
      }
    }
  } else {
    int col = b - 64, k = d;
    float w = W2[k * 256 + col];
    unsigned short hi = f2bf_rne(w);
    float hif = __uint_as_float((unsigned)hi << 16);
    unsigned short lo = f2bf_rne(w - hif);
    B2T[col * 768 + k] = hi;
    B2T[col * 768 + 256 + k] = lo;
    B2T[col * 768 + 512 + k] = hi;
  }
}

// Fused layers 1-3: block b (of 512, 512 thr) handles c2 rows [8b,8b+8) —
// all sharing one c1 (= b>>1). Half hf (t>>8) owns 4 rows. Layer 1 exact
// (libm sinf); layer 2 sin30 (injects <=5e-3 at output); layer-3 dot exact;
// epilogue via angle addition + exact bf16 split Ah+Al.
__global__ void __launch_bounds__(512) k_h123(
    const float* __restrict__ W0, const float* __restrict__ b0,
    const float* __restrict__ Wh0, const float* __restrict__ bh0,
    const float* __restrict__ W1, const float* __restrict__ b1,
    const float* __restrict__ Mf, const float* __restrict__ T2C,
    const float* __restrict__ T2S,
    unsigned short* __restrict__ Ah, unsigned short* __restrict__ Al) {
  __shared__ float xs1[256];
  __shared__ float xs2[8][256];
  int b = blockIdx.x, t = threadIdx.x;
  int d = t & 255, hf = t >> 8;
  int c1 = b >> 1;
  int i1base = (b & 1) * 8 + hf * 4;
  // ---- layer 1 (libm sinf, exact chain); half 0 publishes ----
  if (hf == 0) {
    float lvx = (float)((c1 >> 6) & 3), lvy = (float)((c1 >> 4) & 3);
    int i0 = c1 & 15;
    float tt = fbar(lvx * W0[d]);
    tt = __builtin_fmaf(lvy, W0[256 + d], tt);
    tt = fbar(tt + b0[d]);
    float p = fbar(30.0f * Mf[i0 * 256 + d]);
    float xv = fbar(tt + p);
    xs1[d] = sinf(fbar(30.0f * xv));
  }
  __syncthreads();
  // ---- layer 2 (sin30); dot exact sequential, redundant per half ----
  float acc = 0.0f;
  for (int k = 0; k < 256; ++k)
    acc = __builtin_fmaf(xs1[k], Wh0[k * 256 + d], acc);
  float t2 = fbar(acc + bh0[d]);
#pragma unroll
  for (int rr = 0; rr < 4; ++rr) {
    int i1 = i1base + rr;
    float pp = fbar(30.0f * Mf[4096 + i1 * 256 + d]);
    float x2 = fbar(t2 + pp);
    xs2[hf * 4 + rr][d] = sin30(x2);
  }
  __syncthreads();
  // ---- layer 3 dot (exact sequential) over this half's 4 rows ----
  float acc3[4] = {0.f, 0.f, 0.f, 0.f};
  for (int k = 0; k < 256; ++k) {
    float w = W1[k * 256 + d];
#pragma unroll
    for (int r = 0; r < 4; ++r)
      acc3[r] = __builtin_fmaf(xs2[hf * 4 + r][k], w, acc3[r]);
  }
  // ---- epilogue: angle addition + bf16 split ----
  float tcv[16], tsv[16];
#pragma unroll
  for (int i = 0; i < 16; ++i) {
    tcv[i] = T2C[i * 256 + d];
    tsv[i] = T2S[i * 256 + d];
  }
  float bias = b1[d];
#pragma unroll
  for (int rr = 0; rr < 4; ++rr) {
    float targ = fbar(acc3[rr] + bias);
    float sT, cT;
    sincos30(targ, &sT, &cT);
    int c3base = (b * 8 + hf * 4 + rr) * 16;
#pragma unroll
    for (int i = 0; i < 16; ++i) {
      float hv = __builtin_fmaf(cT, tsv[i], sT * tcv[i]);
      unsigned short hi = f2bf_rne(hv);
      float hif = __uint_as_float((unsigned)hi << 16);
      unsigned short lo = f2bf_rne(hv - hif);
      size_t o = (size_t)(c3base + i) * 256 + d;
      Ah[o] = hi;
      Al[o] = lo;
    }
  }
}

// Layer-4 GEMM: 64x256 tile, 256 thr (4 waves), grid 1024 -> 4 blocks/CU.
// global_load_lds(16B) -> double-buffered LDS (40KB) with 2-way granule
// swizzle; sincos epilogue stores packed bf16 (s,c) pairs, dwordx4-coalesced
// with permuted columns.
__global__ void __launch_bounds__(256, 4) k_gemm(
    const unsigned short* __restrict__ Ah, const unsigned short* __restrict__ Al,
    const unsigned short* __restrict__ B2T, const float* __restrict__ b2,
    unsigned* __restrict__ SC) {
  __shared__ unsigned short As[2][64 * 32];    //  4 KB x2
  __shared__ unsigned short Bs[2][256 * 32];   // 16 KB x2
  const int t = threadIdx.x;
  const int lane = t & 63, wid = t >> 6;
  const int l15 = lane & 15, l4 = lane >> 4;
  const int wn = wid * 64;
  const size_t r0 = (size_t)blockIdx.x * 64;

  const int arow = t >> 2, apart = t & 3;
  const int gpart = (apart - ((arow >> 1) & 3)) & 3;  // pre-swizzled granule

  f32x4 acc[4][4];
#pragma unroll
  for (int rf = 0; rf < 4; ++rf)
#pragma unroll
    for (int cf = 0; cf < 4; ++cf) acc[rf][cf] = (f32x4){0.f, 0.f, 0.f, 0.f};

#define STAGE(c, bb)                                                          \
  {                                                                           \
    const unsigned short* asrc = ((c) >= 16) ? Al : Ah;                       \
    gload16(asrc + ((r0 + arow) << 8) + ((c) & 7) * 32 + gpart * 8,           \
            (void*)(&As[bb][wid * 512]));                                     \
    _Pragma("unroll")                                                         \
    for (int x = 0; x < 4; ++x)                                               \
      gload16(B2T + (size_t)(arow + 64 * x) * 768 + (c) * 32 + gpart * 8,     \
              (void*)(&Bs[bb][(x * 4 + wid) * 512]));                         \
  }

  STAGE(0, 0);
  __syncthreads();   // vmcnt(0) drain: buf0 ready
  const int sp8 = ((l4 + (l15 >> 1)) & 3) * 8;   // read-side swizzle
#pragma unroll 1
  for (int c = 0; c < 24; ++c) {
    int cur = c & 1;
    if (c < 23) STAGE(c + 1, cur ^ 1);   // DMA overlaps this chunk's compute
    bf16x8 af[4], bfr[4];
#pragma unroll
    for (int rf = 0; rf < 4; ++rf)
      af[rf] = __builtin_bit_cast(
          bf16x8, *(const i32x4*)(&As[cur][(rf * 16 + l15) * 32 + sp8]));
#pragma unroll
    for (int cf = 0; cf < 4; ++cf)
      bfr[cf] = __builtin_bit_cast(
          bf16x8, *(const i32x4*)(&Bs[cur][(wn + cf * 16 + l15) * 32 + sp8]));
#pragma unroll
    for (int rf = 0; rf < 4; ++rf)
#pragma unroll
      for (int cf = 0; cf < 4; ++cf)
        acc[rf][cf] = __builtin_amdgcn_mfma_f32_16x16x32_bf16(
            af[rf], bfr[cf], acc[rf][cf], 0, 0, 0);
    __syncthreads();   // drains next-chunk DMA + this chunk's ds_reads
  }
#undef STAGE

  float bias[4];
#pragma unroll
  for (int cf = 0; cf < 4; ++cf) bias[cf] = b2[wn + cf * 16 + l15];
#pragma unroll
  for (int rf = 0; rf < 4; ++rf) {
#pragma unroll
    for (int j = 0; j < 4; ++j) {
      unsigned pk[4];
#pragma unroll
      for (int cf = 0; cf < 4; ++cf) {
        float g = acc[rf][cf][j] + bias[cf];
        float s, c;
        sincos30(g, &s, &c);
        pk[cf] = ((unsigned)f2bf_rne(s) << 16) | (unsigned)f2bf_rne(c);
      }
      size_t row = r0 + rf * 16 + l4 * 4 + j;
      *(i32x4*)(SC + row * 256 + wn + l15 * 4) =
          (i32x4){(int)pk[0], (int)pk[1], (int)pk[2], (int)pk[3]};
    }
  }
}

// Final-layer GEMM: U[c3][col] = sum_k SCbf[c3][k] * B2[col][k],
// M=65536 K=512 N=48 (K in the permuted order shared by SC and B2u).
__global__ void __launch_bounds__(512, 1) k_ugemm(
    const unsigned short* __restrict__ SCb, const unsigned* __restrict__ B2u,
    float* __restrict__ U) {
  __shared__ unsigned short As[128 * 40];
  __shared__ unsigned Bs[48 * 260];
  const int t = threadIdx.x;
  const int lane = t & 63, wid = t >> 6;
  const int l15 = lane & 15, l4 = lane >> 4;
  const int wm = wid * 16;
  const size_t r0 = (size_t)blockIdx.x * 128;

#pragma unroll
  for (int i = 0; i < 24; ++i) {
    int lin = t + i * 512;
    int col = lin >> 8, kp = lin & 255;
    Bs[col * 260 + kp] = B2u[lin];
  }

  const int s_row = t >> 2, s_part = t & 3;
  f32x4 acc[3];
#pragma unroll
  for (int cf = 0; cf < 3; ++cf) acc[cf] = (f32x4){0.f, 0.f, 0.f, 0.f};

  i32x4 ra = *(const i32x4*)(SCb + (r0 + s_row) * 512 + s_part * 8);
#pragma unroll 1
  for (int c = 0; c < 16; ++c) {
    *(i32x4*)(As + s_row * 40 + s_part * 8) = ra;
    __syncthreads();
    if (c < 15)
      ra = *(const i32x4*)(SCb + (r0 + s_row) * 512 + (c + 1) * 32 + s_part * 8);
    bf16x8 af = __builtin_bit_cast(
        bf16x8, *(const i32x4*)(As + (wm + l15) * 40 + l4 * 8));
#pragma unroll
    for (int cf = 0; cf < 3; ++cf) {
      bf16x8 bfr = __builtin_bit_cast(
          bf16x8, *(const i32x4*)(Bs + (cf * 16 + l15) * 260 + c * 16 + l4 * 4));
      acc[cf] = __builtin_amdgcn_mfma_f32_16x16x32_bf16(af, bfr, acc[cf], 0, 0, 0);
    }
    __syncthreads();
  }

#pragma unroll
  for (int cf = 0; cf < 3; ++cf) {
    size_t rbase = r0 + wm + l4 * 4;
#pragma unroll
    for (int j = 0; j < 4; ++j)
      U[(rbase + j) * 48 + cf * 16 + l15] = acc[cf][j];
  }
}

// Per point: 12B lookup out[n] = U[c3][i3*3..+2] + bl.
__global__ void k_gather(const int* __restrict__ coords, const float* __restrict__ U,
                         const float* __restrict__ bl, float* __restrict__ out, int N) {
  int n = blockIdx.x * blockDim.x + threadIdx.x;
  if (n >= N) return;
  int x = coords[2 * n], y = coords[2 * n + 1];
  int c1 = ((x >> 8) & 3) * 64 + ((y >> 8) & 3) * 16 +
           (((y >> 6) & 3) * 4 + ((x >> 6) & 3));
  int i1 = ((y >> 4) & 3) * 4 + ((x >> 4) & 3);
  int i2 = ((y >> 2) & 3) * 4 + ((x >> 2) & 3);
  int i3 = (y & 3) * 4 + (x & 3);
  int c3 = (c1 * 16 + i1) * 16 + i2;
  const float* up = U + (size_t)c3 * 48 + i3 * 3;
  out[n * 3 + 0] = up[0] + bl[0];
  out[n * 3 + 1] = up[1] + bl[1];
  out[n * 3 + 2] = up[2] + bl[2];
}

// -------- fallback (ws too small): exact-f32 direct, block per point --------
__global__ void k_direct(const int* __restrict__ coords, const float* __restrict__ W0,
                         const float* __restrict__ b0, const float* __restrict__ Wh,
                         const float* __restrict__ bh, const float* __restrict__ emb,
                         const float* __restrict__ modW, const float* __restrict__ Wl,
                         const float* __restrict__ bl, float* __restrict__ out) {
  __shared__ float xs[256];
  __shared__ float red[256];
  int n = blockIdx.x, d = threadIdx.x;
  int x = coords[2 * n], y = coords[2 * n + 1];
  float lvx = (float)((x >> 8) & 3), lvy = (float)((y >> 8) & 3);
  int idx[4];
  idx[0] = ((y >> 6) & 3) * 4 + ((x >> 6) & 3);
  idx[1] = ((y >> 4) & 3) * 4 + ((x >> 4) & 3);
  idx[2] = ((y >> 2) & 3) * 4 + ((x >> 2) & 3);
  idx[3] = (y & 3) * 4 + (x & 3);
  float m = 0.0f;
#pragma unroll
  for (int e = 0; e < 16; ++e)
    m = __builtin_fmaf(emb[idx[0] * 16 + e], modW[e * 256 + d], m);
  float t = fbar(lvx * W0[d]);
  t = __builtin_fmaf(lvy, W0[256 + d], t);
  t = fbar(t + b0[d]);
  float p = fbar(30.0f * m);
  float xv = fbar(t + p);
  xs[d] = sinf(fbar(30.0f * xv));
  __syncthreads();
  for (int j = 0; j < 3; ++j) {
    float acc = 0.0f;
    for (int k = 0; k < 256; ++k)
      acc = __builtin_fmaf(xs[k], Wh[j * 65536 + k * 256 + d], acc);
    float tt = fbar(acc + bh[j * 256 + d]);
    m = 0.0f;
#pragma unroll
    for (int e = 0; e < 16; ++e)
      m = __builtin_fmaf(emb[(j + 1) * 256 + idx[j + 1] * 16 + e],
                         modW[((j + 1) * 16 + e) * 256 + d], m);
    p = fbar(30.0f * m);
    xv = fbar(tt + p);
    float h = sinf(fbar(30.0f * xv));
    __syncthreads();
    xs[d] = h;
    __syncthreads();
  }
  for (int q = 0; q < 3; ++q) {
    red[d] = xs[d] * Wl[d * 3 + q];
    __syncthreads();
    for (int s = 128; s > 0; s >>= 1) {
      if (d < s) red[d] += red[d + s];
      __syncthreads();
    }
    if (d == 0) out[n * 3 + q] = red[0] + bl[q];
    __syncthreads();
  }
}

// -------------------- launch --------------------
extern "C" void kernel_launch(void* const* d_in, const int* in_sizes, int n_in,
                              void* d_out, int out_size, void* d_ws, size_t ws_size,
                              hipStream_t stream) {
  const int*   coords = (const int*)d_in[0];
  const float* W0   = (const float*)d_in[1];
  const float* b0   = (const float*)d_in[2];
  const float* Wh   = (const float*)d_in[3];
  const float* bh   = (const float*)d_in[4];
  const float* emb  = (const float*)d_in[5];
  const float* modW = (const float*)d_in[6];
  const float* Wl   = (const float*)d_in[7];
  const float* bl   = (const float*)d_in[8];
  float* out = (float*)d_out;
  const int N = in_sizes[0] / 2;

  // layout: Mf | B2T | Ah | Al | SC | B2u | T2C | T2S  (U overlays dead Ah)
  const size_t OFF_MF  = 0;          //  65536
  const size_t OFF_B2T = 65536;      //  393216
  const size_t OFF_AH  = 458752;     //  33554432
  const size_t OFF_AL  = 34013184;   //  33554432
  const size_t OFF_SC  = 67567616;   //  67108864
  const size_t OFF_B2  = 134676480;  //  98304
  const size_t OFF_T2C = 134774784;  //  16384
  const size_t OFF_T2S = 134791168;  //  16384
  const size_t OFF_U   = OFF_AH;     //  12582912 (overlays Ah, dead after k_gemm)
  const size_t NEED    = 134807552;

  if (ws_size >= NEED) {
    char* ws = (char*)d_ws;
    float*          Mf  = (float*)(ws + OFF_MF);
    unsigned short* B2T = (unsigned short*)(ws + OFF_B2T);
    unsigned short* Ahp = (unsigned short*)(ws + OFF_AH);
    unsigned short* Alp = (unsigned short*)(ws + OFF_AL);
    unsigned*       SC  = (unsigned*)(ws + OFF_SC);
    unsigned*       B2u = (unsigned*)(ws + OFF_B2);
    float*          T2C = (float*)(ws + OFF_T2C);
    float*          T2S = (float*)(ws + OFF_T2S);
    float*          U   = (float*)(ws + OFF_U);

    k_prep<<<320, 256, 0, stream>>>(emb, modW, Mf, T2C, T2S, Wl, B2u,
                                    Wh + 131072, B2T);
    k_h123<<<512, 512, 0, stream>>>(W0, b0, Wh, bh, Wh + 65536, bh + 256, Mf,
                                    T2C, T2S, Ahp, Alp);
    k_gemm<<<1024, 256, 0, stream>>>(Ahp, Alp, B2T, bh + 512, SC);
    k_ugemm<<<512, 512, 0, stream>>>((const unsigned short*)SC, B2u, U);
    k_gather<<<(N + 255) / 256, 256, 0, stream>>>(coords, U, bl, out, N);
  } else {
    k_direct<<<N, 256, 0, stream>>>(coords, W0, b0, Wh, bh, emb, modW, Wl, bl, out);
  }
}

// Round 14
// 104.210 us; speedup vs baseline: 1.1230x; 1.1230x over previous
//
#include <hip/hip_runtime.h>
#include <hip/hip_bf16.h>
#include <math.h>

// Modulated SIREN over 2-bit coordinate fields. Reference is a float32
// re-execution; network is chaotic (layer-1 sin errors amplify ~3e5 to the
// output, layer-2 ~1.5e4) so layer 1 keeps libm sinf + exact f32 chain;
// layer 2 uses sin30 (~3e-7 abs, injects <=2e-2); layers 3-4 use
// sincos30 + angle-addition tables.
// Layer-4 GEMM on MFMA via exact bf16 2-term split (K=768: [Ah,Ah,Al]@
// [Bh;Bl;Bh]), 128x256 tile / 512 thr / grid 512 (round-12 proven shape),
// global_load_lds(16B) double-buffered LDS with 2-way granule swizzle
// (bank-conflict-free, verified). Epilogue stores packed bf16 (s,c) pairs
// dwordx4-coalesced with permuted columns p=(d&0xC0)|((d&15)<<2)|((d>>4)&3);
// B2u uses the same K-permutation (k_ugemm is permutation-invariant).
// Final layer: U = SCbf @ B2^T -> every (c3,i3) answer; point = 12B lookup.

typedef float  f32x4  __attribute__((ext_vector_type(4)));
typedef int    i32x4  __attribute__((ext_vector_type(4)));
typedef __bf16 bf16x8 __attribute__((ext_vector_type(8)));

__device__ __forceinline__ float fbar(float v) {
  asm volatile("" : "+v"(v));
  return v;
}

__device__ __forceinline__ unsigned short f2bf_rne(float x) {
  unsigned u = __float_as_uint(x);
  unsigned r = (u + 0x7fffu + ((u >> 16) & 1u)) >> 16;
  return (unsigned short)r;
}

// async global->LDS, 16B per lane; LDS dest = wave-uniform base + lane*16
__device__ __forceinline__ void gload16(const void* g, void* l) {
  __builtin_amdgcn_global_load_lds(
      (const __attribute__((address_space(1))) unsigned*)g,
      (__attribute__((address_space(3))) unsigned*)l, 16, 0, 0);
}

// sin(30*x): double-single range reduction by 30/2pi, rint half-period fold,
// deg-11 odd Taylor, parity sign. ~3e-7 abs.
__device__ __forceinline__ float sin30(float x) {
  const float Ch = 4.774648189544678f;
  const float Cl = 1.0321218e-07f;
  float revh = x * Ch;
  fbar(revh);
  float e    = __builtin_fmaf(x, Ch, -revh);
  float revl = __builtin_fmaf(x, Cl, e);
  float k2   = __builtin_rintf(revh + revh);
  float g    = __builtin_fmaf(k2, -0.5f, revh) + revl;
  float g2 = g * g;
  float r = -15.0946f;
  r = __builtin_fmaf(r, g2, 42.0601f);
  r = __builtin_fmaf(r, g2, -76.70585f);
  r = __builtin_fmaf(r, g2, 81.6052492f);
  r = __builtin_fmaf(r, g2, -41.341702f);
  r = __builtin_fmaf(r, g2, 6.2831853f);
  float s = g * r;
  int ki = (int)k2;
  return __uint_as_float(__float_as_uint(s) ^ ((unsigned)(ki & 1) << 31));
}

// sin(30*x) AND cos(30*x): shared range reduction, odd+even Taylor polys.
__device__ __forceinline__ void sincos30(float x, float* so, float* co) {
  const float Ch = 4.774648189544678f;
  const float Cl = 1.0321218e-07f;
  float revh = x * Ch;
  fbar(revh);
  float e    = __builtin_fmaf(x, Ch, -revh);
  float revl = __builtin_fmaf(x, Cl, e);
  float k2   = __builtin_rintf(revh + revh);
  float g    = __builtin_fmaf(k2, -0.5f, revh) + revl;
  float u = g * g;
  float sr = -15.0946f;
  sr = __builtin_fmaf(sr, u, 42.0601f);
  sr = __builtin_fmaf(sr, u, -76.70585f);
  sr = __builtin_fmaf(sr, u, 81.6052492f);
  sr = __builtin_fmaf(sr, u, -41.341702f);
  sr = __builtin_fmaf(sr, u, 6.2831853f);
  float s = g * sr;
  float cr = -26.4259f;
  cr = __builtin_fmaf(cr, u, 60.2446f);
  cr = __builtin_fmaf(cr, u, -85.4568f);
  cr = __builtin_fmaf(cr, u, 64.9393940f);
  cr = __builtin_fmaf(cr, u, -19.7392088f);
  float c = __builtin_fmaf(cr, u, 1.0f);
  int ki = (int)k2;
  unsigned sgn = ((unsigned)(ki & 1)) << 31;
  *so = __uint_as_float(__float_as_uint(s) ^ sgn);
  *co = __uint_as_float(__float_as_uint(c) ^ sgn);
}

// Fused prep:
//  blocks 0-63   : Mf[j][i] = emb[j][i]@modW[j] (exact seq fma).
//                  j==2 -> also T2C/T2S (layer-3 angle tables)
//                  j==3 -> also B2u (final-layer B, K-permuted like SC)
//  blocks 64-319 : B2T split [Bh;Bl;Bh] for the layer-4 GEMM.
__global__ void k_prep(const float* __restrict__ emb, const float* __restrict__ modW,
                       float* __restrict__ Mf, float* __restrict__ T2C,
                       float* __restrict__ T2S, const float* __restrict__ Wl,
                       unsigned* __restrict__ B2u, const float* __restrict__ W2,
                       unsigned short* __restrict__ B2T) {
  int b = blockIdx.x, d = threadIdx.x;
  if (b < 64) {
    int j = b >> 4, i = b & 15;
    float acc = 0.0f;
#pragma unroll
    for (int e = 0; e < 16; ++e)
      acc = __builtin_fmaf(emb[j * 256 + i * 16 + e], modW[(j * 16 + e) * 256 + d], acc);
    Mf[b * 256 + d] = acc;
    if (j == 2) {
      float pm = fbar(30.0f * acc);
      float s, c;
      sincos30(pm, &s, &c);
      T2C[i * 256 + d] = c;
      T2S[i * 256 + d] = s;
    } else if (j == 3) {
      float pm = fbar(30.0f * acc);
      float s, c;
      sincos30(pm, &s, &c);
      // same column permutation as k_gemm's SC store
      int p = (d & 0xC0) | ((d & 15) << 2) | ((d >> 4) & 3);
#pragma unroll
      for (int q = 0; q < 3; ++q) {
        float w = Wl[d * 3 + q];
        unsigned ts = (unsigned)f2bf_rne(s * w);
        unsigned tc = (unsigned)f2bf_rne(c * w);
        B2u[(i * 3 + q) * 256 + p] = (tc << 16) | ts;
      }
    }
  } else {
    int col = b - 64, k = d;
    float w = W2[k * 256 + col];
    unsigned short hi = f2bf_rne(w);
    float hif = __uint_as_float((unsigned)hi << 16);
    unsigned short lo = f2bf_rne(w - hif);
    B2T[col * 768 + k] = hi;
    B2T[col * 768 + 256 + k] = lo;
    B2T[col * 768 + 512 + k] = hi;
  }
}

// Fused layers 1-3: block b (of 512, 512 thr) handles c2 rows [8b,8b+8) —
// all sharing one c1 (= b>>1). Half hf (t>>8) owns 4 rows. Layer 1 exact
// (libm sinf); layer 2 sin30; layer-3 dot exact; epilogue via angle
// addition + exact bf16 split Ah+Al.
__global__ void __launch_bounds__(512) k_h123(
    const float* __restrict__ W0, const float* __restrict__ b0,
    const float* __restrict__ Wh0, const float* __restrict__ bh0,
    const float* __restrict__ W1, const float* __restrict__ b1,
    const float* __restrict__ Mf, const float* __restrict__ T2C,
    const float* __restrict__ T2S,
    unsigned short* __restrict__ Ah, unsigned short* __restrict__ Al) {
  __shared__ float xs1[256];
  __shared__ float xs2[8][256];
  int b = blockIdx.x, t = threadIdx.x;
  int d = t & 255, hf = t >> 8;
  int c1 = b >> 1;
  int i1base = (b & 1) * 8 + hf * 4;
  // ---- layer 1 (libm sinf, exact chain); half 0 publishes ----
  if (hf == 0) {
    float lvx = (float)((c1 >> 6) & 3), lvy = (float)((c1 >> 4) & 3);
    int i0 = c1 & 15;
    float tt = fbar(lvx * W0[d]);
    tt = __builtin_fmaf(lvy, W0[256 + d], tt);
    tt = fbar(tt + b0[d]);
    float p = fbar(30.0f * Mf[i0 * 256 + d]);
    float xv = fbar(tt + p);
    xs1[d] = sinf(fbar(30.0f * xv));
  }
  __syncthreads();
  // ---- layer 2 (sin30); dot exact sequential, redundant per half ----
  float acc = 0.0f;
  for (int k = 0; k < 256; ++k)
    acc = __builtin_fmaf(xs1[k], Wh0[k * 256 + d], acc);
  float t2 = fbar(acc + bh0[d]);
#pragma unroll
  for (int rr = 0; rr < 4; ++rr) {
    int i1 = i1base + rr;
    float pp = fbar(30.0f * Mf[4096 + i1 * 256 + d]);
    float x2 = fbar(t2 + pp);
    xs2[hf * 4 + rr][d] = sin30(x2);
  }
  __syncthreads();
  // ---- layer 3 dot (exact sequential) over this half's 4 rows ----
  float acc3[4] = {0.f, 0.f, 0.f, 0.f};
  for (int k = 0; k < 256; ++k) {
    float w = W1[k * 256 + d];
#pragma unroll
    for (int r = 0; r < 4; ++r)
      acc3[r] = __builtin_fmaf(xs2[hf * 4 + r][k], w, acc3[r]);
  }
  // ---- epilogue: angle addition + bf16 split ----
  float tcv[16], tsv[16];
#pragma unroll
  for (int i = 0; i < 16; ++i) {
    tcv[i] = T2C[i * 256 + d];
    tsv[i] = T2S[i * 256 + d];
  }
  float bias = b1[d];
#pragma unroll
  for (int rr = 0; rr < 4; ++rr) {
    float targ = fbar(acc3[rr] + bias);
    float sT, cT;
    sincos30(targ, &sT, &cT);
    int c3base = (b * 8 + hf * 4 + rr) * 16;
#pragma unroll
    for (int i = 0; i < 16; ++i) {
      float hv = __builtin_fmaf(cT, tsv[i], sT * tcv[i]);
      unsigned short hi = f2bf_rne(hv);
      float hif = __uint_as_float((unsigned)hi << 16);
      unsigned short lo = f2bf_rne(hv - hif);
      size_t o = (size_t)(c3base + i) * 256 + d;
      Ah[o] = hi;
      Al[o] = lo;
    }
  }
}

// Layer-4 GEMM (round-12 proven shape): 128x256 tile, 512 thr (8 waves 2x4),
// grid 512. global_load_lds(16B) -> double-buffered LDS with 2-way granule
// swizzle (conflict-free); sincos epilogue stores packed bf16 (s,c) pairs,
// dwordx4-coalesced with permuted columns.
__global__ void __launch_bounds__(512, 1) k_gemm(
    const unsigned short* __restrict__ Ah, const unsigned short* __restrict__ Al,
    const unsigned short* __restrict__ B2T, const float* __restrict__ b2,
    unsigned* __restrict__ SC) {
  __shared__ unsigned short As[2][128 * 32];
  __shared__ unsigned short Bs[2][256 * 32];
  const int t = threadIdx.x;
  const int lane = t & 63, wid = t >> 6;
  const int l15 = lane & 15, l4 = lane >> 4;
  const int wm = (wid >> 2) * 64;
  const int wn = (wid & 3) * 64;
  const size_t r0 = (size_t)blockIdx.x * 128;

  const int arow = t >> 2, apart = t & 3;
  const int gpart = (apart - ((arow >> 1) & 3)) & 3;   // pre-swizzled granule
  const size_t bcol0 = t >> 2, bcol1 = (t >> 2) + 128; // (bcol>>1)&3 == (arow>>1)&3

  f32x4 acc[4][4];
#pragma unroll
  for (int rf = 0; rf < 4; ++rf)
#pragma unroll
    for (int cf = 0; cf < 4; ++cf) acc[rf][cf] = (f32x4){0.f, 0.f, 0.f, 0.f};

#define STAGE(c, bb)                                                         \
  {                                                                          \
    const unsigned short* asrc = ((c) >= 16) ? Al : Ah;                      \
    gload16(asrc + ((r0 + arow) << 8) + ((c) & 7) * 32 + gpart * 8,          \
            (void*)(&As[bb][wid * 512]));                                    \
    gload16(B2T + bcol0 * 768 + (c) * 32 + gpart * 8,                        \
            (void*)(&Bs[bb][wid * 512]));                                    \
    gload16(B2T + bcol1 * 768 + (c) * 32 + gpart * 8,                        \
            (void*)(&Bs[bb][(wid + 8) * 512]));                              \
  }

  STAGE(0, 0);
  __syncthreads();   // vmcnt(0) drain: buf0 ready
  const int sp8 = ((l4 + (l15 >> 1)) & 3) * 8;   // read-side swizzle
#pragma unroll 1
  for (int c = 0; c < 24; ++c) {
    int cur = c & 1;
    if (c < 23) STAGE(c + 1, cur ^ 1);   // DMA overlaps this chunk's compute
    bf16x8 af[4], bfr[4];
#pragma unroll
    for (int rf = 0; rf < 4; ++rf)
      af[rf] = __builtin_bit_cast(
          bf16x8, *(const i32x4*)(&As[cur][(wm + rf * 16 + l15) * 32 + sp8]));
#pragma unroll
    for (int cf = 0; cf < 4; ++cf)
      bfr[cf] = __builtin_bit_cast(
          bf16x8, *(const i32x4*)(&Bs[cur][(wn + cf * 16 + l15) * 32 + sp8]));
#pragma unroll
    for (int rf = 0; rf < 4; ++rf)
#pragma unroll
      for (int cf = 0; cf < 4; ++cf)
        acc[rf][cf] = __builtin_amdgcn_mfma_f32_16x16x32_bf16(
            af[rf], bfr[cf], acc[rf][cf], 0, 0, 0);
    __syncthreads();   // drains next-chunk DMA + this chunk's ds_reads
  }
#undef STAGE

  float bias[4];
#pragma unroll
  for (int cf = 0; cf < 4; ++cf) bias[cf] = b2[wn + cf * 16 + l15];
#pragma unroll
  for (int rf = 0; rf < 4; ++rf) {
#pragma unroll
    for (int j = 0; j < 4; ++j) {
      unsigned pk[4];
#pragma unroll
      for (int cf = 0; cf < 4; ++cf) {
        float g = acc[rf][cf][j] + bias[cf];
        float s, c;
        sincos30(g, &s, &c);
        pk[cf] = ((unsigned)f2bf_rne(s) << 16) | (unsigned)f2bf_rne(c);
      }
      size_t row = r0 + wm + rf * 16 + l4 * 4 + j;
      *(i32x4*)(SC + row * 256 + wn + l15 * 4) =
          (i32x4){(int)pk[0], (int)pk[1], (int)pk[2], (int)pk[3]};
    }
  }
}

// Final-layer GEMM: U[c3][col] = sum_k SCbf[c3][k] * B2[col][k],
// M=65536 K=512 N=48 (K in the permuted order shared by SC and B2u).
__global__ void __launch_bounds__(512, 1) k_ugemm(
    const unsigned short* __restrict__ SCb, const unsigned* __restrict__ B2u,
    float* __restrict__ U) {
  __shared__ unsigned short As[128 * 40];
  __shared__ unsigned Bs[48 * 260];
  const int t = threadIdx.x;
  const int lane = t & 63, wid = t >> 6;
  const int l15 = lane & 15, l4 = lane >> 4;
  const int wm = wid * 16;
  const size_t r0 = (size_t)blockIdx.x * 128;

#pragma unroll
  for (int i = 0; i < 24; ++i) {
    int lin = t + i * 512;
    int col = lin >> 8, kp = lin & 255;
    Bs[col * 260 + kp] = B2u[lin];
  }

  const int s_row = t >> 2, s_part = t & 3;
  f32x4 acc[3];
#pragma unroll
  for (int cf = 0; cf < 3; ++cf) acc[cf] = (f32x4){0.f, 0.f, 0.f, 0.f};

  i32x4 ra = *(const i32x4*)(SCb + (r0 + s_row) * 512 + s_part * 8);
#pragma unroll 1
  for (int c = 0; c < 16; ++c) {
    *(i32x4*)(As + s_row * 40 + s_part * 8) = ra;
    __syncthreads();
    if (c < 15)
      ra = *(const i32x4*)(SCb + (r0 + s_row) * 512 + (c + 1) * 32 + s_part * 8);
    bf16x8 af = __builtin_bit_cast(
        bf16x8, *(const i32x4*)(As + (wm + l15) * 40 + l4 * 8));
#pragma unroll
    for (int cf = 0; cf < 3; ++cf) {
      bf16x8 bfr = __builtin_bit_cast(
          bf16x8, *(const i32x4*)(Bs + (cf * 16 + l15) * 260 + c * 16 + l4 * 4));
      acc[cf] = __builtin_amdgcn_mfma_f32_16x16x32_bf16(af, bfr, acc[cf], 0, 0, 0);
    }
    __syncthreads();
  }

#pragma unroll
  for (int cf = 0; cf < 3; ++cf) {
    size_t rbase = r0 + wm + l4 * 4;
#pragma unroll
    for (int j = 0; j < 4; ++j)
      U[(rbase + j) * 48 + cf * 16 + l15] = acc[cf][j];
  }
}

// Per point: 12B lookup out[n] = U[c3][i3*3..+2] + bl.
__global__ void k_gather(const int* __restrict__ coords, const float* __restrict__ U,
                         const float* __restrict__ bl, float* __restrict__ out, int N) {
  int n = blockIdx.x * blockDim.x + threadIdx.x;
  if (n >= N) return;
  int x = coords[2 * n], y = coords[2 * n + 1];
  int c1 = ((x >> 8) & 3) * 64 + ((y >> 8) & 3) * 16 +
           (((y >> 6) & 3) * 4 + ((x >> 6) & 3));
  int i1 = ((y >> 4) & 3) * 4 + ((x >> 4) & 3);
  int i2 = ((y >> 2) & 3) * 4 + ((x >> 2) & 3);
  int i3 = (y & 3) * 4 + (x & 3);
  int c3 = (c1 * 16 + i1) * 16 + i2;
  const float* up = U + (size_t)c3 * 48 + i3 * 3;
  out[n * 3 + 0] = up[0] + bl[0];
  out[n * 3 + 1] = up[1] + bl[1];
  out[n * 3 + 2] = up[2] + bl[2];
}

// -------- fallback (ws too small): exact-f32 direct, block per point --------
__global__ void k_direct(const int* __restrict__ coords, const float* __restrict__ W0,
                         const float* __restrict__ b0, const float* __restrict__ Wh,
                         const float* __restrict__ bh, const float* __restrict__ emb,
                         const float* __restrict__ modW, const float* __restrict__ Wl,
                         const float* __restrict__ bl, float* __restrict__ out) {
  __shared__ float xs[256];
  __shared__ float red[256];
  int n = blockIdx.x, d = threadIdx.x;
  int x = coords[2 * n], y = coords[2 * n + 1];
  float lvx = (float)((x >> 8) & 3), lvy = (float)((y >> 8) & 3);
  int idx[4];
  idx[0] = ((y >> 6) & 3) * 4 + ((x >> 6) & 3);
  idx[1] = ((y >> 4) & 3) * 4 + ((x >> 4) & 3);
  idx[2] = ((y >> 2) & 3) * 4 + ((x >> 2) & 3);
  idx[3] = (y & 3) * 4 + (x & 3);
  float m = 0.0f;
#pragma unroll
  for (int e = 0; e < 16; ++e)
    m = __builtin_fmaf(emb[idx[0] * 16 + e], modW[e * 256 + d], m);
  float t = fbar(lvx * W0[d]);
  t = __builtin_fmaf(lvy, W0[256 + d], t);
  t = fbar(t + b0[d]);
  float p = fbar(30.0f * m);
  float xv = fbar(t + p);
  xs[d] = sinf(fbar(30.0f * xv));
  __syncthreads();
  for (int j = 0; j < 3; ++j) {
    float acc = 0.0f;
    for (int k = 0; k < 256; ++k)
      acc = __builtin_fmaf(xs[k], Wh[j * 65536 + k * 256 + d], acc);
    float tt = fbar(acc + bh[j * 256 + d]);
    m = 0.0f;
#pragma unroll
    for (int e = 0; e < 16; ++e)
      m = __builtin_fmaf(emb[(j + 1) * 256 + idx[j + 1] * 16 + e],
                         modW[((j + 1) * 16 + e) * 256 + d], m);
    p = fbar(30.0f * m);
    xv = fbar(tt + p);
    float h = sinf(fbar(30.0f * xv));
    __syncthreads();
    xs[d] = h;
    __syncthreads();
  }
  for (int q = 0; q < 3; ++q) {
    red[d] = xs[d] * Wl[d * 3 + q];
    __syncthreads();
    for (int s = 128; s > 0; s >>= 1) {
      if (d < s) red[d] += red[d + s];
      __syncthreads();
    }
    if (d == 0) out[n * 3 + q] = red[0] + bl[q];
    __syncthreads();
  }
}

// -------------------- launch --------------------
extern "C" void kernel_launch(void* const* d_in, const int* in_sizes, int n_in,
                              void* d_out, int out_size, void* d_ws, size_t ws_size,
                              hipStream_t stream) {
  const int*   coords = (const int*)d_in[0];
  const float* W0   = (const float*)d_in[1];
  const float* b0   = (const float*)d_in[2];
  const float* Wh   = (const float*)d_in[3];
  const float* bh   = (const float*)d_in[4];
  const float* emb  = (const float*)d_in[5];
  const float* modW = (const float*)d_in[6];
  const float* Wl   = (const float*)d_in[7];
  const float* bl   = (const float*)d_in[8];
  float* out = (float*)d_out;
  const int N = in_sizes[0] / 2;

  // layout: Mf | B2T | Ah | Al | SC | B2u | T2C | T2S  (U overlays dead Ah)
  const size_t OFF_MF  = 0;          //  65536
  const size_t OFF_B2T = 65536;      //  393216
  const size_t OFF_AH  = 458752;     //  33554432
  const size_t OFF_AL  = 34013184;   //  33554432
  const size_t OFF_SC  = 67567616;   //  67108864
  const size_t OFF_B2  = 134676480;  //  98304
  const size_t OFF_T2C = 134774784;  //  16384
  const size_t OFF_T2S = 134791168;  //  16384
  const size_t OFF_U   = OFF_AH;     //  12582912 (overlays Ah, dead after k_gemm)
  const size_t NEED    = 134807552;

  if (ws_size >= NEED) {
    char* ws = (char*)d_ws;
    float*          Mf  = (float*)(ws + OFF_MF);
    unsigned short* B2T = (unsigned short*)(ws + OFF_B2T);
    unsigned short* Ahp = (unsigned short*)(ws + OFF_AH);
    unsigned short* Alp = (unsigned short*)(ws + OFF_AL);
    unsigned*       SC  = (unsigned*)(ws + OFF_SC);
    unsigned*       B2u = (unsigned*)(ws + OFF_B2);
    float*          T2C = (float*)(ws + OFF_T2C);
    float*          T2S = (float*)(ws + OFF_T2S);
    float*          U   = (float*)(ws + OFF_U);

    k_prep<<<320, 256, 0, stream>>>(emb, modW, Mf, T2C, T2S, Wl, B2u,
                                    Wh + 131072, B2T);
    k_h123<<<512, 512, 0, stream>>>(W0, b0, Wh, bh, Wh + 65536, bh + 256, Mf,
                                    T2C, T2S, Ahp, Alp);
    k_gemm<<<512, 512, 0, stream>>>(Ahp, Alp, B2T, bh + 512, SC);
    k_ugemm<<<512, 512, 0, stream>>>((const unsigned short*)SC, B2u, U);
    k_gather<<<(N + 255) / 256, 256, 0, stream>>>(coords, U, bl, out, N);
  } else {
    k_direct<<<N, 256, 0, stream>>>(coords, W0, b0, Wh, bh, emb, modW, Wl, bl, out);
  }
}